// Round 9
// baseline (259.203 us; speedup 1.0000x reference)
//
#include <hip/hip_runtime.h>
#include <math.h>
#include <stdint.h>

#define N_PTS 2048
#define I_DIM 16
#define H_DIM 64
#define O_DIM 64
#define NCUTS 8
#define NGROUPS 4
#define GN_EPS 1e-5f
#define GN_TOT 32768.0f   // 16 ch * 2048 pts per group

typedef __attribute__((ext_vector_type(8))) short short8;
typedef __attribute__((ext_vector_type(4))) float f32x4;
typedef __attribute__((ext_vector_type(4))) uint32_t u32x4;

__device__ inline uint32_t cvt_pk_bf16(float lo, float hi) {
    uint32_t r;
    asm("v_cvt_pk_bf16_f32 %0, %1, %2" : "=v"(r) : "v"(lo), "v"(hi));
    return r;
}

__device__ inline short8 frag_of(uint32_t a, uint32_t b, uint32_t c, uint32_t d) {
    u32x4 t; t.x = a; t.y = b; t.z = c; t.w = d;
    return __builtin_bit_cast(short8, t);
}

__device__ inline float bf16hi_to_f(uint32_t w) {          // bits 31:16 are the bf16
    return __builtin_bit_cast(float, w & 0xFFFF0000u);
}
__device__ inline float bf16lo_to_f(uint32_t w) {
    return __builtin_bit_cast(float, w << 16);
}

// ---------------------------------------------------------------------------
// k_front: fused  pack(points,nuv -> pjp)  +  input MLP  +  GN1 stats atomics
// 512 blocks x 256 threads; block = 4 points x 64 channels.
// ---------------------------------------------------------------------------
__global__ __launch_bounds__(256) void k_front(
    const float* __restrict__ points, const float* __restrict__ nuv,
    const float* __restrict__ features, const float* __restrict__ W1,
    const float* __restrict__ b1, const float* __restrict__ W2,
    const float* __restrict__ b2, float* __restrict__ out,
    float* __restrict__ pjp, float* __restrict__ stats)
{
    __shared__ float f0s[4][H_DIM];
    __shared__ float sred[16], qred[16];
    const float SC = 0.70710678118654752f;
    int tid = threadIdx.x;
    int pl = tid >> 6, h = tid & 63;
    int n = blockIdx.x * 4 + pl;

    // pack pjp[n] = {x*SC,y*SC,z*SC,0, nx,ny,nz,0}
    if (h < 3)            pjp[n * 8 + h]     = points[n * 3 + h] * SC;
    else if (h == 3)      pjp[n * 8 + 3]     = 0.f;
    else if (h < 7)       pjp[n * 8 + h]     = nuv[n * 9 + (h - 4)];
    else if (h == 7)      pjp[n * 8 + 7]     = 0.f;

    const float* fr = features + n * I_DIM;
    float s = b1[h];
    #pragma unroll
    for (int i = 0; i < I_DIM; ++i) s = fmaf(fr[i], W1[h * I_DIM + i], s);
    s = s > 0.f ? s : 0.2f * s;
    f0s[pl][h] = s;
    __syncthreads();
    float t = b2[h];
    #pragma unroll
    for (int k = 0; k < H_DIM; ++k) t = fmaf(f0s[pl][k], W2[h * H_DIM + k], t);
    t = t > 0.f ? t : 0.2f * t;
    out[n * H_DIM + h] = t;

    // GN1 stats: reduce within 16-lane channel-group, combine, atomicAdd
    float ss = t, qq = t * t;
    #pragma unroll
    for (int off = 8; off >= 1; off >>= 1) {
        ss += __shfl_xor(ss, off);
        qq += __shfl_xor(qq, off);
    }
    int grp = pl * 4 + (h >> 4);
    if ((h & 15) == 0) { sred[grp] = ss; qred[grp] = qq; }
    __syncthreads();
    if (tid < 4) {
        float S = sred[tid] + sred[4 + tid] + sred[8 + tid] + sred[12 + tid];
        float Q = qred[tid] + qred[4 + tid] + qred[8 + tid] + qred[12 + tid];
        atomicAdd(&stats[tid], S);
        atomicAdd(&stats[4 + tid], Q);
    }
}

// ---------------------------------------------------------------------------
// k_apply1: GN1 apply -> bf16 fbh (packed pairs). 256 blocks x 256 thr,
// each thread handles 2 consecutive elements -> one dword store.
// ---------------------------------------------------------------------------
__global__ __launch_bounds__(256) void k_apply1(
    const float* __restrict__ x, const float* __restrict__ stats,
    const float* __restrict__ w, const float* __restrict__ b,
    uint32_t* __restrict__ fbh)
{
    int idx2 = blockIdx.x * 256 + threadIdx.x;       // dword index
    int e = idx2 * 2;
    int ch = e & 63;
    int g = ch >> 4;
    float m = stats[g] / GN_TOT;
    float var = stats[4 + g] / GN_TOT - m * m;
    float r = rsqrtf(var + GN_EPS);
    float v0 = (x[e]     - m) * r * w[ch]     + b[ch];
    float v1 = (x[e + 1] - m) * r * w[ch + 1] + b[ch + 1];
    fbh[idx2] = cvt_pk_bf16(v0, v1);
}

// ---------------------------------------------------------------------------
// k_conv: pairwise windowed conv via MFMA.
// Block = point i, 4 waves; wave wv owns 64-j tiles jt = wv, wv+4, ...
// Each lane computes the preamble for a DISTINCT j = jt*64 + lane (1x work),
// B-words distributed by __shfl (R4-verified construction).
// f read directly from global bf16 fbh (L2-resident): one uint2 = 4 bf16
// channels per (n,m). Row = jt*64+n*16+jj0 has 64 bf16 = 16 uint2;
// channel offset (m*16+cc0)/4 = m*4 + (cc0>>2).  [R7 bug was dword units]
// D(ch,j) = A(ch,k)*B(k,j); A=(w2|b2) const regs; probed cc0/jj0 pairing.
// out[i,ch] = sum_j relu(D[ch,j]) * f[j][ch].
// ---------------------------------------------------------------------------
__global__ __launch_bounds__(256, 4) void k_conv_mfma(
    const float* __restrict__ pjp, const float* __restrict__ nuv,
    const float* __restrict__ cw1, const float* __restrict__ cb1,
    const float* __restrict__ cw2, const float* __restrict__ cb2,
    const uint32_t* __restrict__ fbh, float* __restrict__ out)
{
    __shared__ float red[4][H_DIM];
    int i   = blockIdx.x;
    int tid = threadIdx.x;
    int lane = tid & 63, wv = tid >> 6;
    int l15 = lane & 15, lg = lane >> 4;

    // ---- layout probes (R4/R6-verified PASS) ---------------------------
    uint32_t one_b = cvt_pk_bf16(1.f, 0.f);
    uint32_t idx_b = cvt_pk_bf16((float)l15, 0.f);
    short8 pIdx = frag_of(lg == 0 ? idx_b : 0u, 0u, 0u, 0u);
    short8 pOne = frag_of(lg == 0 ? one_b : 0u, 0u, 0u, 0u);
    f32x4 Dc = __builtin_amdgcn_mfma_f32_16x16x32_bf16(
        pIdx, pOne, (f32x4){0.f, 0.f, 0.f, 0.f}, 0, 0, 0);
    f32x4 Dj = __builtin_amdgcn_mfma_f32_16x16x32_bf16(
        pOne, pIdx, (f32x4){0.f, 0.f, 0.f, 0.f}, 0, 0, 0);
    int cc[4];
    #pragma unroll
    for (int r = 0; r < 4; ++r) cc[r] = (int)(Dc[r] + 0.5f);
    int cc0 = cc[0];                       // cc[r] = cc0 + r (verified by passes)
    int jj0 = (int)(Dj[0] + 0.5f);         // r-invariant (verified)
    int cc0q = cc0 >> 2;                   // uint2 offset within 16-ch tile

    // ---- per-block (uniform) point-i data ------------------------------
    float pix = pjp[i * 8 + 0];
    float piy = pjp[i * 8 + 1];
    float piz = pjp[i * 8 + 2];
    float nv[9];
    #pragma unroll
    for (int a = 0; a < 9; ++a) nv[a] = nuv[i * 9 + a];
    float w1c[NCUTS][3], bb1[NCUTS];
    #pragma unroll
    for (int c = 0; c < NCUTS; ++c) {
        w1c[c][0] = cw1[c * 3 + 0];
        w1c[c][1] = cw1[c * 3 + 1];
        w1c[c][2] = cw1[c * 3 + 2];
        bb1[c]    = cb1[c];
    }

    // ---- constant A-frags: tile m covers ch = m*16 + (0..15) -----------
    short8 Af[4];
    #pragma unroll
    for (int m = 0; m < 4; ++m) {
        int ch = m * 16 + l15;
        uint32_t a0 = 0, a1 = 0, a2 = 0, a3 = 0;
        if (lg == 0) {
            a0 = cvt_pk_bf16(cw2[ch * 8 + 0], cw2[ch * 8 + 1]);
            a1 = cvt_pk_bf16(cw2[ch * 8 + 2], cw2[ch * 8 + 3]);
            a2 = cvt_pk_bf16(cw2[ch * 8 + 4], cw2[ch * 8 + 5]);
            a3 = cvt_pk_bf16(cw2[ch * 8 + 6], cw2[ch * 8 + 7]);
        } else if (lg == 1) {
            a0 = cvt_pk_bf16(cb2[ch], 0.f);   // k=8 slot: bias row
        }
        Af[m] = frag_of(a0, a1, a2, a3);
    }

    float acc[4][4];
    #pragma unroll
    for (int m = 0; m < 4; ++m)
        #pragma unroll
        for (int r = 0; r < 4; ++r) acc[m][r] = 0.f;

    const uint2* fh = (const uint2*)fbh;

    #pragma unroll 1
    for (int jt = wv; jt < N_PTS / 64; jt += 4) {
        // each lane: preamble for its own distinct j
        int j = jt * 64 + lane;
        f32x4 pa = ((const f32x4*)pjp)[j * 2 + 0];
        f32x4 pb = ((const f32x4*)pjp)[j * 2 + 1];
        float dx = pa.x - pix;
        float dy = pa.y - piy;
        float dz = pa.z - piz;
        float nd = nv[0] * pb.x + nv[1] * pb.y + nv[2] * pb.z;
        float tt = 2.f - nd;
        float d2 = (dx * dx + dy * dy + dz * dz) * tt * tt;
        float win = __expf(-d2);
        float P0 = nv[0] * dx + nv[1] * dy + nv[2] * dz;
        float P1 = nv[3] * dx + nv[4] * dy + nv[5] * dz;
        float P2 = nv[6] * dx + nv[7] * dy + nv[8] * dz;
        float hp[NCUTS];
        #pragma unroll
        for (int c = 0; c < NCUTS; ++c) {
            float v = fmaf(P0, w1c[c][0], fmaf(P1, w1c[c][1], fmaf(P2, w1c[c][2], bb1[c])));
            v = v > 0.f ? v : 0.f;
            hp[c] = win * v;                  // fold window into B
        }
        uint32_t hw0 = cvt_pk_bf16(hp[0], hp[1]);
        uint32_t hw1 = cvt_pk_bf16(hp[2], hp[3]);
        uint32_t hw2 = cvt_pk_bf16(hp[4], hp[5]);
        uint32_t hw3 = cvt_pk_bf16(hp[6], hp[7]);
        uint32_t ww  = cvt_pk_bf16(win, 0.f); // k=8 slot: window (x b2)

        #pragma unroll
        for (int n = 0; n < 4; ++n) {
            int src = n * 16 + l15;           // lane holding this column's j
            uint32_t s0 = (uint32_t)__shfl((int)hw0, src);
            uint32_t s1 = (uint32_t)__shfl((int)hw1, src);
            uint32_t s2 = (uint32_t)__shfl((int)hw2, src);
            uint32_t s3 = (uint32_t)__shfl((int)hw3, src);
            uint32_t sw = (uint32_t)__shfl((int)ww , src);
            short8 Bf = frag_of(
                (lg == 0) ? s0 : ((lg == 1) ? sw : 0u),
                (lg == 0) ? s1 : 0u,
                (lg == 0) ? s2 : 0u,
                (lg == 0) ? s3 : 0u);
            // uint2 index of f[jt*64+n*16+jj0][m*16+cc0 .. +3]
            int e2 = ((jt * 64 + n * 16 + jj0) << 4) + cc0q;
            #pragma unroll
            for (int m = 0; m < 4; ++m) {
                uint2 u = fh[e2 + m * 4];
                f32x4 C = __builtin_amdgcn_mfma_f32_16x16x32_bf16(
                    Af[m], Bf, (f32x4){0.f, 0.f, 0.f, 0.f}, 0, 0, 0);
                float f0 = bf16lo_to_f(u.x);
                float f1 = bf16hi_to_f(u.x);
                float f2 = bf16lo_to_f(u.y);
                float f3 = bf16hi_to_f(u.y);
                float x0 = C[0] > 0.f ? C[0] : 0.f;
                float x1 = C[1] > 0.f ? C[1] : 0.f;
                float x2 = C[2] > 0.f ? C[2] : 0.f;
                float x3 = C[3] > 0.f ? C[3] : 0.f;
                acc[m][0] = fmaf(x0, f0, acc[m][0]);
                acc[m][1] = fmaf(x1, f1, acc[m][1]);
                acc[m][2] = fmaf(x2, f2, acc[m][2]);
                acc[m][3] = fmaf(x3, f3, acc[m][3]);
            }
        }
    }

    // reduce over the 16 j-columns held across l15 (butterfly -> all lanes)
    #pragma unroll
    for (int m = 0; m < 4; ++m)
        #pragma unroll
        for (int r = 0; r < 4; ++r) {
            float v = acc[m][r];
            v += __shfl_xor(v, 1);
            v += __shfl_xor(v, 2);
            v += __shfl_xor(v, 4);
            v += __shfl_xor(v, 8);
            acc[m][r] = v;
        }

    if (l15 == 0) {
        #pragma unroll
        for (int m = 0; m < 4; ++m)
            #pragma unroll
            for (int r = 0; r < 4; ++r)
                red[wv][m * 16 + cc[r]] = acc[m][r];
    }
    __syncthreads();
    if (tid < H_DIM) {
        out[i * H_DIM + tid] = red[0][tid] + red[1][tid] + red[2][tid] + red[3][tid];
    }
}

// ---------------------------------------------------------------------------
// k_back: fused output MLP + GN2 stats atomics
// ---------------------------------------------------------------------------
__global__ __launch_bounds__(256) void k_back(
    const float* __restrict__ fin, const float* __restrict__ W1,
    const float* __restrict__ b1, const float* __restrict__ W2,
    const float* __restrict__ b2, float* __restrict__ out,
    float* __restrict__ stats)
{
    __shared__ float t1s[4][O_DIM];
    __shared__ float sred[16], qred[16];
    int tid = threadIdx.x;
    int pl = tid >> 6, o = tid & 63;
    int n = blockIdx.x * 4 + pl;
    const float* fr = fin + n * H_DIM;
    float s = b1[o];
    #pragma unroll
    for (int k = 0; k < H_DIM; ++k) s = fmaf(fr[k], W1[o * H_DIM + k], s);
    s = s > 0.f ? s : 0.2f * s;
    t1s[pl][o] = s;
    __syncthreads();
    float t = b2[o];
    #pragma unroll
    for (int k = 0; k < O_DIM; ++k) t = fmaf(t1s[pl][k], W2[o * O_DIM + k], t);
    t = t > 0.f ? t : 0.2f * t;
    out[n * O_DIM + o] = t;

    float ss = t, qq = t * t;
    #pragma unroll
    for (int off = 8; off >= 1; off >>= 1) {
        ss += __shfl_xor(ss, off);
        qq += __shfl_xor(qq, off);
    }
    int grp = pl * 4 + (o >> 4);
    if ((o & 15) == 0) { sred[grp] = ss; qred[grp] = qq; }
    __syncthreads();
    if (tid < 4) {
        float S = sred[tid] + sred[4 + tid] + sred[8 + tid] + sred[12 + tid];
        float Q = qred[tid] + qred[4 + tid] + qred[8 + tid] + qred[12 + tid];
        atomicAdd(&stats[tid], S);
        atomicAdd(&stats[4 + tid], Q);
    }
}

// ---------------------------------------------------------------------------
// k_apply2: GN2 apply, f32 in-place on d_out
// ---------------------------------------------------------------------------
__global__ __launch_bounds__(256) void k_apply2(
    float* __restrict__ x, const float* __restrict__ stats,
    const float* __restrict__ w, const float* __restrict__ b)
{
    for (int idx = blockIdx.x * 256 + threadIdx.x; idx < N_PTS * O_DIM;
         idx += gridDim.x * 256) {
        int ch = idx & 63;
        int g = ch >> 4;
        float m = stats[g] / GN_TOT;
        float var = stats[4 + g] / GN_TOT - m * m;
        float r = rsqrtf(var + GN_EPS);
        x[idx] = (x[idx] - m) * r * w[ch] + b[ch];
    }
}

// ---------------------------------------------------------------------------
extern "C" void kernel_launch(void* const* d_in, const int* in_sizes, int n_in,
                              void* d_out, int out_size, void* d_ws, size_t ws_size,
                              hipStream_t stream)
{
    const float* points   = (const float*)d_in[0];
    const float* nuv      = (const float*)d_in[1];
    const float* features = (const float*)d_in[2];
    const float* W_in1    = (const float*)d_in[3];
    const float* b_in1    = (const float*)d_in[4];
    const float* W_in2    = (const float*)d_in[5];
    const float* b_in2    = (const float*)d_in[6];
    const float* gn_in_w  = (const float*)d_in[7];
    const float* gn_in_b  = (const float*)d_in[8];
    const float* cw1      = (const float*)d_in[9];
    const float* cb1      = (const float*)d_in[10];
    const float* cw2      = (const float*)d_in[11];
    const float* cb2      = (const float*)d_in[12];
    const float* W_out1   = (const float*)d_in[13];
    const float* b_out1   = (const float*)d_in[14];
    const float* W_out2   = (const float*)d_in[15];
    const float* b_out2   = (const float*)d_in[16];
    const float* gn_out_w = (const float*)d_in[17];
    const float* gn_out_b = (const float*)d_in[18];

    float*    bufA  = (float*)d_ws;                  // N*64 f32 (MLP/conv out)
    float*    pjp   = bufA + N_PTS * H_DIM;          // N*8 f32 packed pts/normals
    float*    stats = pjp + N_PTS * 8;               // 16 f32 (2 group norms)
    uint32_t* fbh   = (uint32_t*)(stats + 16);       // N*64 bf16 = N*32 dwords
    float*    outp  = (float*)d_out;

    hipMemsetAsync(stats, 0, 16 * sizeof(float), stream);
    k_front    <<<N_PTS / 4, 256, 0, stream>>>(points, nuv, features,
                                               W_in1, b_in1, W_in2, b_in2,
                                               bufA, pjp, stats);
    k_apply1   <<<N_PTS * H_DIM / 512, 256, 0, stream>>>(bufA, stats,
                                               gn_in_w, gn_in_b, fbh);
    k_conv_mfma<<<N_PTS, 256, 0, stream>>>(pjp, nuv, cw1, cb1, cw2, cb2,
                                               fbh, bufA);
    k_back     <<<N_PTS / 4, 256, 0, stream>>>(bufA, W_out1, b_out1,
                                               W_out2, b_out2, outp, stats + 8);
    k_apply2   <<<256, 256, 0, stream>>>(outp, stats + 8, gn_out_w, gn_out_b);
}